// Round 6
// baseline (432.139 us; speedup 1.0000x reference)
//
#include <hip/hip_runtime.h>
#include <hip/hip_bf16.h>

#define N_NODES 100000
#define N_EDGES 3200000
#define IN_F 256
#define OUT_F 128

#define BK_SHIFT 6
#define BK_NODES 64
#define NB 1563            // ceil(100000/64)
#define CAP 4096           // bucket region size (mean 2048, sd ~45 -> 45 sigma)

// Fused hetero kernel: 391 gemm-role blocks (256 nodes each) + 256
// bucket-role blocks, interleaved in dispatch order so each CU co-hosts
// one gemm (MFMA-bound) and one bucket (scatter-latency-bound) block.
// launch_bounds(1024,8) -> <=64 VGPR -> 2 blocks/CU = 32 waves/CU.
#define NGB 391            // ceil(100000/256) gemm blocks
#define NBB 256            // bucket blocks (1/CU; round-1: fewer blocks = coalesced scatter)
#define FUSED_BLOCKS (NGB + NBB)
#define BUCKET_CHUNK 12500 // N_EDGES / NBB exactly
#define BITER 13           // ceil(12500/1024)

// ---------------- workspace layout (bytes) ----------------
#define OFF_H       0UL          // 25,600,000  N_NODES*OUT_F bf16
#define OFF_WT      25600000UL   // 65,536      W^T bf16 [OUT_F][IN_F]
#define OFF_ROWPTR  25665536UL   // 400,004     (unused since fused gather)
#define OFF_BCUR    26065544UL   // 6,252       NB ints
#define OFF_EDGES   26071808UL   // 51,216,384  NB*CAP int2 {src|dstlo<<17, val}
#define WS_NEEDED   77288192UL

typedef unsigned short ushort_t;
typedef __attribute__((ext_vector_type(8))) short short8;
typedef __attribute__((ext_vector_type(4))) float floatx4;

static __device__ __forceinline__ ushort_t f2bf(float f) {
  return __bfloat16_as_ushort(__float2bfloat16(f));
}
static __device__ __forceinline__ unsigned pk2(float a, float b) {
  return (unsigned)f2bf(a) | ((unsigned)f2bf(b) << 16);
}

// ========== prep: wt[f][k] = bf16(W[k][f]) ==========
__global__ __launch_bounds__(256) void wprep_kernel(
    const float* __restrict__ W, ushort_t* __restrict__ wt) {
  const int idx = blockIdx.x * 256 + threadIdx.x;   // 32768 total
  const int k = idx >> 7, f = idx & 127;
  wt[f * IN_F + k] = f2bf(W[k * OUT_F + f]);
}

// ========== fused gemm + bucket (independent inputs -> co-resident) ==========
#define GKC 64
union FusedSM {
  struct {                       // gemm role: 55,296 B
    ushort_t xs[4][64][72];      // 4 tiles of [node][k], +8 pad
    ushort_t wls[128][72];       // [feat][k] +8 pad
  } g;
  struct {                       // bucket role: 12,504 B
    int lh[NB];
    int lb[NB];
  } b;
};

__global__ __launch_bounds__(1024, 8) void gemm_bucket_kernel(
    const float* __restrict__ x, const ushort_t* __restrict__ wt,
    const float* __restrict__ bias, ushort_t* __restrict__ h,
    const int* __restrict__ src, const int* __restrict__ dst,
    const float* __restrict__ vals, int* __restrict__ bcur,
    int2* __restrict__ bedges) {
  __shared__ FusedSM sm;
  const int bid = blockIdx.x;
  const int t = threadIdx.x;

  // role interleave: blocks 1,3,..,511 -> bucket 0..255; rest -> gemm 0..390
  bool is_bucket;
  int rid;
  if (bid < 2 * NBB) { is_bucket = (bid & 1); rid = bid >> 1; }
  else               { is_bucket = false;     rid = bid - 2 * NBB + NBB; }

  if (is_bucket) {
    // ----- bucket role: scatter edges into fixed-stride dst-bucket regions
    const int beg = rid * BUCKET_CHUNK;
    const int end = min(beg + BUCKET_CHUNK, N_EDGES);
    for (int i = t; i < NB; i += 1024) sm.b.lh[i] = 0;
    __syncthreads();
    int dcache[BITER];
#pragma unroll
    for (int i = 0; i < BITER; ++i) {
      const int e = beg + t + i * 1024;
      if (e < end) {
        const int d = dst[e];
        dcache[i] = d;
        atomicAdd(&sm.b.lh[d >> BK_SHIFT], 1);
      } else {
        dcache[i] = -1;
      }
    }
    __syncthreads();
    for (int i = t; i < NB; i += 1024) {
      const int c = sm.b.lh[i];
      sm.b.lb[i] = c ? atomicAdd(&bcur[i], c) : 0;
      sm.b.lh[i] = 0;
    }
    __syncthreads();
#pragma unroll
    for (int i = 0; i < BITER; ++i) {
      const int e = beg + t + i * 1024;
      if (e < end) {
        const int d = dcache[i];
        const int b = d >> BK_SHIFT;
        const int p = sm.b.lb[b] + atomicAdd(&sm.b.lh[b], 1);
        if (p < CAP)
          bedges[(size_t)b * CAP + p] =
              make_int2(src[e] | ((d & 63) << 17), __float_as_int(vals[e]));
      }
    }
    return;
  }

  // ----- gemm role: 256 nodes = 4 tiles x 64 nodes; 16 waves = 4 per tile
  const int nb0 = rid * 256;
  const int tile = t >> 8;          // staging tile (threads 0-255 -> tile 0, ...)
  const int t256 = t & 255;
  const int w = t >> 6, lane = t & 63;
  const int wtile = w >> 2, w4 = w & 3;     // MFMA tile & wave-within-tile
  const int m16 = lane & 15, q8 = (lane >> 4) * 8;

  floatx4 acc[8];
#pragma unroll
  for (int i = 0; i < 8; ++i) acc[i] = (floatx4){0.f, 0.f, 0.f, 0.f};

  for (int kc = 0; kc < IN_F; kc += GKC) {
    {  // stage x tile: thread -> node t256>>2 of its tile, 16 k's at (t256&3)*16
      const int ln = t256 >> 2;
      const int ks = (t256 & 3) * 16;
      const int n = min(nb0 + tile * 64 + ln, N_NODES - 1);  // clamp; epilogue guards
      const float4* xp = reinterpret_cast<const float4*>(&x[(size_t)n * IN_F + kc + ks]);
      {
        const float4 a = xp[0], b = xp[1];
        uint4 u0;
        u0.x = pk2(a.x, a.y); u0.y = pk2(a.z, a.w);
        u0.z = pk2(b.x, b.y); u0.w = pk2(b.z, b.w);
        *reinterpret_cast<uint4*>(&sm.g.xs[tile][ln][ks]) = u0;
      }
      {
        const float4 c = xp[2], d = xp[3];
        uint4 u1;
        u1.x = pk2(c.x, c.y); u1.y = pk2(c.z, c.w);
        u1.z = pk2(d.x, d.y); u1.w = pk2(d.z, d.w);
        *reinterpret_cast<uint4*>(&sm.g.xs[tile][ln][ks + 8]) = u1;
      }
    }
    {  // stage wt chunk once per block: thread -> feat t>>3, 8 k's at (t&7)*8
      const int f = t >> 3;
      const int ks2 = (t & 7) * 8;
      *reinterpret_cast<uint4*>(&sm.g.wls[f][ks2]) =
          *reinterpret_cast<const uint4*>(&wt[f * IN_F + kc + ks2]);
    }
    __syncthreads();
#pragma unroll
    for (int kk = 0; kk < GKC; kk += 32) {
      const short8 af = *reinterpret_cast<const short8*>(&sm.g.xs[wtile][16 * w4 + m16][kk + q8]);
#pragma unroll
      for (int ct = 0; ct < 8; ++ct) {
        const short8 bf = *reinterpret_cast<const short8*>(&sm.g.wls[ct * 16 + m16][kk + q8]);
        acc[ct] = __builtin_amdgcn_mfma_f32_16x16x32_bf16(af, bf, acc[ct], 0, 0, 0);
      }
    }
    __syncthreads();
  }
  // epilogue: C/D col=lane&15, row=(lane>>4)*4+reg
  float bv[8];
#pragma unroll
  for (int ct = 0; ct < 8; ++ct) bv[ct] = bias[ct * 16 + m16];
#pragma unroll
  for (int ct = 0; ct < 8; ++ct) {
#pragma unroll
    for (int r = 0; r < 4; ++r) {
      const int node = nb0 + wtile * 64 + 16 * w4 + (lane >> 4) * 4 + r;
      if (node < N_NODES)
        h[(size_t)node * OUT_F + ct * 16 + m16] = f2bf(acc[ct][r] + bv[ct]);
    }
  }
}

// ========== standalone GEMM (fallback path only) ==========
__global__ __launch_bounds__(256) void gemm_mfma_kernel(
    const float* __restrict__ x, const ushort_t* __restrict__ wt,
    const float* __restrict__ bias, ushort_t* __restrict__ h) {
  __shared__ ushort_t xs[64][72];
  __shared__ ushort_t wls[128][72];
  const int t = threadIdx.x;
  const int n0 = blockIdx.x * 64;
  const int w = t >> 6, lane = t & 63;
  const int m16 = lane & 15, q8 = (lane >> 4) * 8;

  floatx4 acc[8];
#pragma unroll
  for (int i = 0; i < 8; ++i) acc[i] = (floatx4){0.f, 0.f, 0.f, 0.f};

  for (int kc = 0; kc < IN_F; kc += GKC) {
    {
      const int ln = t >> 2;
      const int ks = (t & 3) * 16;
      const int n = min(n0 + ln, N_NODES - 1);
      const float4* xp = reinterpret_cast<const float4*>(&x[(size_t)n * IN_F + kc + ks]);
      const float4 a = xp[0], b = xp[1], c = xp[2], d = xp[3];
      uint4 u0, u1;
      u0.x = pk2(a.x, a.y); u0.y = pk2(a.z, a.w);
      u0.z = pk2(b.x, b.y); u0.w = pk2(b.z, b.w);
      u1.x = pk2(c.x, c.y); u1.y = pk2(c.z, c.w);
      u1.z = pk2(d.x, d.y); u1.w = pk2(d.z, d.w);
      *reinterpret_cast<uint4*>(&xs[ln][ks]) = u0;
      *reinterpret_cast<uint4*>(&xs[ln][ks + 8]) = u1;
    }
    {
      const int f = t >> 1;
      const int ks = (t & 1) * 32;
      const uint4* wp = reinterpret_cast<const uint4*>(&wt[f * IN_F + kc + ks]);
#pragma unroll
      for (int j = 0; j < 4; ++j)
        *reinterpret_cast<uint4*>(&wls[f][ks + 8 * j]) = wp[j];
    }
    __syncthreads();
#pragma unroll
    for (int kk = 0; kk < GKC; kk += 32) {
      const short8 af = *reinterpret_cast<const short8*>(&xs[16 * w + m16][kk + q8]);
#pragma unroll
      for (int ct = 0; ct < 8; ++ct) {
        const short8 bf = *reinterpret_cast<const short8*>(&wls[ct * 16 + m16][kk + q8]);
        acc[ct] = __builtin_amdgcn_mfma_f32_16x16x32_bf16(af, bf, acc[ct], 0, 0, 0);
      }
    }
    __syncthreads();
  }
  float bv[8];
#pragma unroll
  for (int ct = 0; ct < 8; ++ct) bv[ct] = bias[ct * 16 + m16];
#pragma unroll
  for (int ct = 0; ct < 8; ++ct) {
#pragma unroll
    for (int r = 0; r < 4; ++r) {
      const int node = n0 + 16 * w + (lane >> 4) * 4 + r;
      if (node < N_NODES)
        h[(size_t)node * OUT_F + ct * 16 + m16] = f2bf(acc[ct][r] + bv[ct]);
    }
  }
}

// ========== fused sort+gather: one block per bucket ==========
__global__ __launch_bounds__(1024, 8) void gather_fused_kernel(
    const int* __restrict__ bcur, const int2* __restrict__ bedges,
    const ushort_t* __restrict__ h, float* __restrict__ out) {
  __shared__ int2 se[CAP];                 // raw bucket edges      32 KB
  __shared__ int2 se2[CAP];                // node-sorted edges     32 KB
  __shared__ int hist[BK_NODES];
  __shared__ int cur[BK_NODES];
  __shared__ int nstart[BK_NODES + 1];
  const int b = blockIdx.x;
  const int t = threadIdx.x;
  const int n0 = b << BK_SHIFT;
  const size_t base = (size_t)b * CAP;
  const int cnt = min(bcur[b], CAP);

  if (t < BK_NODES) hist[t] = 0;
  __syncthreads();

  for (int i = t; i < cnt; i += 1024) {
    const int2 p = bedges[base + i];
    se[i] = p;
    atomicAdd(&hist[(p.x >> 17) & 63], 1);
  }
  __syncthreads();

  if (t < BK_NODES) {  // wave 0: inclusive scan over 64 counters
    const int v = hist[t];
    int inc = v;
    for (int off = 1; off < 64; off <<= 1) {
      const int u = __shfl_up(inc, off, 64);
      if (t >= off) inc += u;
    }
    nstart[t] = inc - v;
    cur[t] = inc - v;
    if (t == BK_NODES - 1) nstart[BK_NODES] = inc;
  }
  __syncthreads();

  for (int i = t; i < cnt; i += 1024) {
    const int2 p = se[i];
    const int d = (p.x >> 17) & 63;
    const int pos = atomicAdd(&cur[d], 1);
    se2[pos] = make_int2(p.x & 0x1FFFF, p.y);
  }
  __syncthreads();

  // gather: group g = t>>4 owns node n0+g; 16 lanes x 8 feats
  const int g = t >> 4;
  const int n = n0 + g;
  const int f = (t & 15) * 8;
  const int beg = nstart[g];
  const int end = nstart[g + 1];

  float acc[8];
#pragma unroll
  for (int i = 0; i < 8; ++i) acc[i] = 0.f;

#define BF16_MAC(u, v)                                                        \
  {                                                                           \
    acc[0] += (v) * __uint_as_float((u).x << 16);                             \
    acc[1] += (v) * __uint_as_float((u).x & 0xFFFF0000u);                     \
    acc[2] += (v) * __uint_as_float((u).y << 16);                             \
    acc[3] += (v) * __uint_as_float((u).y & 0xFFFF0000u);                     \
    acc[4] += (v) * __uint_as_float((u).z << 16);                             \
    acc[5] += (v) * __uint_as_float((u).z & 0xFFFF0000u);                     \
    acc[6] += (v) * __uint_as_float((u).w << 16);                             \
    acc[7] += (v) * __uint_as_float((u).w & 0xFFFF0000u);                     \
  }

  int e = beg;
  for (; e + 3 < end; e += 4) {
    const int2 p0 = se2[e + 0];           // 16-lane same-address ds_read: broadcast
    const int2 p1 = se2[e + 1];
    const int2 p2 = se2[e + 2];
    const int2 p3 = se2[e + 3];
    uint4 hv[4];
    hv[0] = *reinterpret_cast<const uint4*>(&h[(size_t)p0.x * OUT_F + f]);
    hv[1] = *reinterpret_cast<const uint4*>(&h[(size_t)p1.x * OUT_F + f]);
    hv[2] = *reinterpret_cast<const uint4*>(&h[(size_t)p2.x * OUT_F + f]);
    hv[3] = *reinterpret_cast<const uint4*>(&h[(size_t)p3.x * OUT_F + f]);
    BF16_MAC(hv[0], __int_as_float(p0.y));
    BF16_MAC(hv[1], __int_as_float(p1.y));
    BF16_MAC(hv[2], __int_as_float(p2.y));
    BF16_MAC(hv[3], __int_as_float(p3.y));
  }
  for (; e < end; ++e) {
    const int2 p = se2[e];
    const uint4 hv = *reinterpret_cast<const uint4*>(&h[(size_t)p.x * OUT_F + f]);
    BF16_MAC(hv, __int_as_float(p.y));
  }
#undef BF16_MAC

  if (n < N_NODES) {
    floatx4 o0 = {acc[0], acc[1], acc[2], acc[3]};
    floatx4 o1 = {acc[4], acc[5], acc[6], acc[7]};
    __builtin_nontemporal_store(o0, reinterpret_cast<floatx4*>(&out[(size_t)n * OUT_F + f]));
    __builtin_nontemporal_store(o1, reinterpret_cast<floatx4*>(&out[(size_t)n * OUT_F + f + 4]));
  }
}

// ========== fallback atomic scatter (ws too small; h bf16) ==========
__global__ __launch_bounds__(256) void scatter_kernel(
    const int* __restrict__ src, const int* __restrict__ dst,
    const float* __restrict__ vals, const ushort_t* __restrict__ h,
    float* __restrict__ out) {
  const int lane = threadIdx.x & 63;
  const int wave = (blockIdx.x * blockDim.x + threadIdx.x) >> 6;
  const int nwaves = (gridDim.x * blockDim.x) >> 6;
  for (int e = wave; e < N_EDGES; e += nwaves) {
    const int s = src[e];
    const int d = dst[e];
    const float v = vals[e];
    const unsigned int u = *reinterpret_cast<const unsigned int*>(&h[(size_t)s * OUT_F + lane * 2]);
    float* op = &out[(size_t)d * OUT_F + lane * 2];
    atomicAdd(op + 0, v * __uint_as_float(u << 16));
    atomicAdd(op + 1, v * __uint_as_float(u & 0xFFFF0000u));
  }
}

extern "C" void kernel_launch(void* const* d_in, const int* in_sizes, int n_in,
                              void* d_out, int out_size, void* d_ws, size_t ws_size,
                              hipStream_t stream) {
  const float* x        = (const float*)d_in[0];
  const int*   edge_src = (const int*)d_in[1];
  const int*   edge_dst = (const int*)d_in[2];
  const float* edge_vals= (const float*)d_in[3];
  const float* weight   = (const float*)d_in[4];
  const float* bias     = (const float*)d_in[5];
  float* out = (float*)d_out;

  char* ws = (char*)d_ws;
  ushort_t* h   = (ushort_t*)(ws + OFF_H);
  ushort_t* wt  = (ushort_t*)(ws + OFF_WT);
  int* bcur     = (int*)(ws + OFF_BCUR);
  int2* bedges  = (int2*)(ws + OFF_EDGES);

  // 1) W^T to bf16
  wprep_kernel<<<128, 256, 0, stream>>>(weight, wt);

  if (ws_size >= WS_NEEDED) {
    // 2) fused: h = bf16(x@W+b) via MFMA  ||  bucket edges (independent inputs,
    //    co-resident blocks: MFMA-bound + scatter-latency-bound overlap)
    hipMemsetAsync(bcur, 0, NB * sizeof(int), stream);
    gemm_bucket_kernel<<<FUSED_BLOCKS, 1024, 0, stream>>>(
        x, wt, bias, h, edge_src, edge_dst, edge_vals, bcur, bedges);
    // 3) fused LDS sort + atomic-free gather (one block per bucket)
    gather_fused_kernel<<<NB, 1024, 0, stream>>>(bcur, bedges, h, out);
  } else {
    gemm_mfma_kernel<<<(N_NODES + 63) / 64, 256, 0, stream>>>(x, wt, bias, h);
    hipMemsetAsync(d_out, 0, (size_t)out_size * sizeof(float), stream);
    scatter_kernel<<<8192, 256, 0, stream>>>(edge_src, edge_dst, edge_vals, h, out);
  }
}

// Round 7
// 392.208 us; speedup vs baseline: 1.1018x; 1.1018x over previous
//
#include <hip/hip_runtime.h>
#include <hip/hip_bf16.h>

#define N_NODES 100000
#define N_EDGES 3200000
#define IN_F 256
#define OUT_F 128

#define BK_SHIFT 6
#define BK_NODES 64
#define NB 1563            // ceil(100000/64)
#define CAP 4096           // bucket region size (mean 2048, sd ~45 -> 45 sigma)

// bucket grid: 256 blocks (1/CU) keeps ~8 edges/bucket/block -> coalesced
// 64B-line scatter writes (round-1: 2048 blocks destroyed coalescing; round-6:
// co-residency with gemm's streaming destroyed it too -> bucket runs ALONE).
// Occupancy via BLOCK SIZE: 1024 thr = 16 waves/CU.
#define BUCKET_BLOCKS 256
#define BT 1024
#define BITER 13           // ceil((3200000/256)/1024) = ceil(12500/1024)

// ---------------- workspace layout (bytes) ----------------
#define OFF_H       0UL          // 25,600,000  N_NODES*OUT_F bf16
#define OFF_WT      25600000UL   // 65,536      W^T bf16 [OUT_F][IN_F]
#define OFF_ROWPTR  25665536UL   // 400,004     (unused since fused gather)
#define OFF_BCUR    26065544UL   // 6,252       NB ints
#define OFF_EDGES   26071808UL   // 51,216,384  NB*CAP int2 {src|dstlo<<17, val}
#define WS_NEEDED   77288192UL

typedef unsigned short ushort_t;
typedef __attribute__((ext_vector_type(8))) short short8;
typedef __attribute__((ext_vector_type(4))) float floatx4;

static __device__ __forceinline__ ushort_t f2bf(float f) {
  return __bfloat16_as_ushort(__float2bfloat16(f));
}
static __device__ __forceinline__ unsigned pk2(float a, float b) {
  return (unsigned)f2bf(a) | ((unsigned)f2bf(b) << 16);
}

// ========== prep: wt[f][k] = bf16(W[k][f]) ==========
__global__ __launch_bounds__(256) void wprep_kernel(
    const float* __restrict__ W, ushort_t* __restrict__ wt) {
  const int idx = blockIdx.x * 256 + threadIdx.x;   // 32768 total
  const int k = idx >> 7, f = idx & 127;
  wt[f * IN_F + k] = f2bf(W[k * OUT_F + f]);
}

// ========== GEMM: h(bf16) = x@W + bias via MFMA ==========
// 64 nodes/block, 4 waves; wave w: nodes [16w,16w+16), all 128 feats
// (8 col-tiles of 16). K-chunks of 64 staged in LDS (x cvt to bf16).
// Launched LAST before gather so h is freshest in L2/L3 (round-7 reorder:
// bucket's 133MB stream no longer evicts h between gemm and gather).
#define GKC 64
__global__ __launch_bounds__(256) void gemm_mfma_kernel(
    const float* __restrict__ x, const ushort_t* __restrict__ wt,
    const float* __restrict__ bias, ushort_t* __restrict__ h) {
  __shared__ ushort_t xs[64][72];    // [node][k] +8 pad (144B stride: 2-way alias, free)
  __shared__ ushort_t wls[128][72];  // [feat][k] +8 pad
  const int t = threadIdx.x;
  const int n0 = blockIdx.x * 64;
  const int w = t >> 6, lane = t & 63;
  const int m16 = lane & 15, q8 = (lane >> 4) * 8;

  floatx4 acc[8];
#pragma unroll
  for (int i = 0; i < 8; ++i) acc[i] = (floatx4){0.f, 0.f, 0.f, 0.f};

  for (int kc = 0; kc < IN_F; kc += GKC) {
    {  // stage x tile: thread -> node t>>2, 16 k's at (t&3)*16
      const int ln = t >> 2;
      const int ks = (t & 3) * 16;
      const int n = min(n0 + ln, N_NODES - 1);  // clamp避OOB; epilogue guards
      const float4* xp = reinterpret_cast<const float4*>(&x[(size_t)n * IN_F + kc + ks]);
      const float4 a = xp[0], b = xp[1], c = xp[2], d = xp[3];
      uint4 u0, u1;
      u0.x = pk2(a.x, a.y); u0.y = pk2(a.z, a.w);
      u0.z = pk2(b.x, b.y); u0.w = pk2(b.z, b.w);
      u1.x = pk2(c.x, c.y); u1.y = pk2(c.z, c.w);
      u1.z = pk2(d.x, d.y); u1.w = pk2(d.z, d.w);
      *reinterpret_cast<uint4*>(&xs[ln][ks]) = u0;
      *reinterpret_cast<uint4*>(&xs[ln][ks + 8]) = u1;
    }
    {  // stage wt chunk: thread -> feat t>>1, 32 k's at (t&1)*32
      const int f = t >> 1;
      const int ks = (t & 1) * 32;
      const uint4* wp = reinterpret_cast<const uint4*>(&wt[f * IN_F + kc + ks]);
#pragma unroll
      for (int j = 0; j < 4; ++j)
        *reinterpret_cast<uint4*>(&wls[f][ks + 8 * j]) = wp[j];
    }
    __syncthreads();
#pragma unroll
    for (int kk = 0; kk < GKC; kk += 32) {
      // A frag: A[m=lane&15][k=kk+q8..+8]
      const short8 af = *reinterpret_cast<const short8*>(&xs[16 * w + m16][kk + q8]);
#pragma unroll
      for (int ct = 0; ct < 8; ++ct) {
        // B frag: B[k=kk+q8..+8][n=ct*16+(lane&15)] from wt[n][k]
        const short8 bf = *reinterpret_cast<const short8*>(&wls[ct * 16 + m16][kk + q8]);
        acc[ct] = __builtin_amdgcn_mfma_f32_16x16x32_bf16(af, bf, acc[ct], 0, 0, 0);
      }
    }
    __syncthreads();
  }
  // epilogue: C/D col=lane&15, row=(lane>>4)*4+reg
  float bv[8];
#pragma unroll
  for (int ct = 0; ct < 8; ++ct) bv[ct] = bias[ct * 16 + m16];
#pragma unroll
  for (int ct = 0; ct < 8; ++ct) {
#pragma unroll
    for (int r = 0; r < 4; ++r) {
      const int node = n0 + 16 * w + (lane >> 4) * 4 + r;
      if (node < N_NODES)
        h[(size_t)node * OUT_F + ct * 16 + m16] = f2bf(acc[ct][r] + bv[ct]);
    }
  }
}

// ========== bucket: scatter edges into fixed-stride dst-bucket regions ==========
// 1024 threads, 16 waves/CU; dst cached in registers across both passes
// (fixed BITER unroll keeps dcache in VGPRs, not scratch).
__global__ __launch_bounds__(BT) void bucket_kernel(
    const int* __restrict__ src, const int* __restrict__ dst,
    const float* __restrict__ vals, int* __restrict__ bcur,
    int2* __restrict__ bedges) {
  __shared__ int lh[NB];
  __shared__ int lb[NB];
  const int t = threadIdx.x;
  const int chunk = (N_EDGES + gridDim.x - 1) / gridDim.x;
  const int beg = blockIdx.x * chunk;
  const int end = min(beg + chunk, N_EDGES);
  for (int i = t; i < NB; i += BT) lh[i] = 0;
  __syncthreads();
  int dcache[BITER];
#pragma unroll
  for (int i = 0; i < BITER; ++i) {
    const int e = beg + t + i * BT;
    if (e < end) {
      const int d = dst[e];
      dcache[i] = d;
      atomicAdd(&lh[d >> BK_SHIFT], 1);
    } else {
      dcache[i] = -1;
    }
  }
  __syncthreads();
  for (int i = t; i < NB; i += BT) {
    const int c = lh[i];
    lb[i] = c ? atomicAdd(&bcur[i], c) : 0;
    lh[i] = 0;
  }
  __syncthreads();
#pragma unroll
  for (int i = 0; i < BITER; ++i) {
    const int e = beg + t + i * BT;
    if (e < end) {
      const int d = dcache[i];
      const int b = d >> BK_SHIFT;
      const int p = lb[b] + atomicAdd(&lh[b], 1);
      if (p < CAP)
        bedges[(size_t)b * CAP + p] = make_int2(src[e] | ((d & 63) << 17), __float_as_int(vals[e]));
    }
  }
}

// ========== fused sort+gather: one block per bucket ==========
// LDS counting-sort then direct gather. bedges is read EXACTLY ONCE here
// (into LDS), so non-temporal staging loads are safe (round-3's nt failure
// was global re-reads) and keep the 25.6MB edge stream from evicting h.
__global__ __launch_bounds__(1024, 8) void gather_fused_kernel(
    const int* __restrict__ bcur, const int2* __restrict__ bedges,
    const ushort_t* __restrict__ h, float* __restrict__ out) {
  __shared__ int2 se[CAP];                 // raw bucket edges      32 KB
  __shared__ int2 se2[CAP];                // node-sorted edges     32 KB
  __shared__ int hist[BK_NODES];
  __shared__ int cur[BK_NODES];
  __shared__ int nstart[BK_NODES + 1];
  const int b = blockIdx.x;
  const int t = threadIdx.x;
  const int n0 = b << BK_SHIFT;
  const size_t base = (size_t)b * CAP;
  const int cnt = min(bcur[b], CAP);

  if (t < BK_NODES) hist[t] = 0;
  __syncthreads();

  const unsigned long long* bp = reinterpret_cast<const unsigned long long*>(bedges);
  for (int i = t; i < cnt; i += 1024) {
    const unsigned long long r = __builtin_nontemporal_load(bp + base + i);
    int2 p;
    p.x = (int)(unsigned)r;
    p.y = (int)(unsigned)(r >> 32);
    se[i] = p;
    atomicAdd(&hist[(p.x >> 17) & 63], 1);
  }
  __syncthreads();

  if (t < BK_NODES) {  // wave 0: inclusive scan over 64 counters
    const int v = hist[t];
    int inc = v;
    for (int off = 1; off < 64; off <<= 1) {
      const int u = __shfl_up(inc, off, 64);
      if (t >= off) inc += u;
    }
    nstart[t] = inc - v;
    cur[t] = inc - v;
    if (t == BK_NODES - 1) nstart[BK_NODES] = inc;
  }
  __syncthreads();

  for (int i = t; i < cnt; i += 1024) {
    const int2 p = se[i];
    const int d = (p.x >> 17) & 63;
    const int pos = atomicAdd(&cur[d], 1);
    se2[pos] = make_int2(p.x & 0x1FFFF, p.y);
  }
  __syncthreads();

  // gather: group g = t>>4 owns node n0+g; 16 lanes x 8 feats
  const int g = t >> 4;
  const int n = n0 + g;
  const int f = (t & 15) * 8;
  const int beg = nstart[g];
  const int end = nstart[g + 1];

  float acc[8];
#pragma unroll
  for (int i = 0; i < 8; ++i) acc[i] = 0.f;

#define BF16_MAC(u, v)                                                        \
  {                                                                           \
    acc[0] += (v) * __uint_as_float((u).x << 16);                             \
    acc[1] += (v) * __uint_as_float((u).x & 0xFFFF0000u);                     \
    acc[2] += (v) * __uint_as_float((u).y << 16);                             \
    acc[3] += (v) * __uint_as_float((u).y & 0xFFFF0000u);                     \
    acc[4] += (v) * __uint_as_float((u).z << 16);                             \
    acc[5] += (v) * __uint_as_float((u).z & 0xFFFF0000u);                     \
    acc[6] += (v) * __uint_as_float((u).w << 16);                             \
    acc[7] += (v) * __uint_as_float((u).w & 0xFFFF0000u);                     \
  }

  int e = beg;
  for (; e + 3 < end; e += 4) {
    const int2 p0 = se2[e + 0];           // 16-lane same-address ds_read: broadcast
    const int2 p1 = se2[e + 1];
    const int2 p2 = se2[e + 2];
    const int2 p3 = se2[e + 3];
    uint4 hv[4];
    hv[0] = *reinterpret_cast<const uint4*>(&h[(size_t)p0.x * OUT_F + f]);
    hv[1] = *reinterpret_cast<const uint4*>(&h[(size_t)p1.x * OUT_F + f]);
    hv[2] = *reinterpret_cast<const uint4*>(&h[(size_t)p2.x * OUT_F + f]);
    hv[3] = *reinterpret_cast<const uint4*>(&h[(size_t)p3.x * OUT_F + f]);
    BF16_MAC(hv[0], __int_as_float(p0.y));
    BF16_MAC(hv[1], __int_as_float(p1.y));
    BF16_MAC(hv[2], __int_as_float(p2.y));
    BF16_MAC(hv[3], __int_as_float(p3.y));
  }
  for (; e < end; ++e) {
    const int2 p = se2[e];
    const uint4 hv = *reinterpret_cast<const uint4*>(&h[(size_t)p.x * OUT_F + f]);
    BF16_MAC(hv, __int_as_float(p.y));
  }
#undef BF16_MAC

  if (n < N_NODES) {
    floatx4 o0 = {acc[0], acc[1], acc[2], acc[3]};
    floatx4 o1 = {acc[4], acc[5], acc[6], acc[7]};
    __builtin_nontemporal_store(o0, reinterpret_cast<floatx4*>(&out[(size_t)n * OUT_F + f]));
    __builtin_nontemporal_store(o1, reinterpret_cast<floatx4*>(&out[(size_t)n * OUT_F + f + 4]));
  }
}

// ========== fallback atomic scatter (ws too small; h bf16) ==========
__global__ __launch_bounds__(256) void scatter_kernel(
    const int* __restrict__ src, const int* __restrict__ dst,
    const float* __restrict__ vals, const ushort_t* __restrict__ h,
    float* __restrict__ out) {
  const int lane = threadIdx.x & 63;
  const int wave = (blockIdx.x * blockDim.x + threadIdx.x) >> 6;
  const int nwaves = (gridDim.x * blockDim.x) >> 6;
  for (int e = wave; e < N_EDGES; e += nwaves) {
    const int s = src[e];
    const int d = dst[e];
    const float v = vals[e];
    const unsigned int u = *reinterpret_cast<const unsigned int*>(&h[(size_t)s * OUT_F + lane * 2]);
    float* op = &out[(size_t)d * OUT_F + lane * 2];
    atomicAdd(op + 0, v * __uint_as_float(u << 16));
    atomicAdd(op + 1, v * __uint_as_float(u & 0xFFFF0000u));
  }
}

extern "C" void kernel_launch(void* const* d_in, const int* in_sizes, int n_in,
                              void* d_out, int out_size, void* d_ws, size_t ws_size,
                              hipStream_t stream) {
  const float* x        = (const float*)d_in[0];
  const int*   edge_src = (const int*)d_in[1];
  const int*   edge_dst = (const int*)d_in[2];
  const float* edge_vals= (const float*)d_in[3];
  const float* weight   = (const float*)d_in[4];
  const float* bias     = (const float*)d_in[5];
  float* out = (float*)d_out;

  char* ws = (char*)d_ws;
  ushort_t* h   = (ushort_t*)(ws + OFF_H);
  ushort_t* wt  = (ushort_t*)(ws + OFF_WT);
  int* bcur     = (int*)(ws + OFF_BCUR);
  int2* bedges  = (int2*)(ws + OFF_EDGES);

  if (ws_size >= WS_NEEDED) {
    // Order: bucket FIRST so its 133MB stream doesn't evict h between gemm
    // and gather; gemm runs immediately before gather (h hot in L2/L3).
    hipMemsetAsync(bcur, 0, NB * sizeof(int), stream);
    bucket_kernel<<<BUCKET_BLOCKS, BT, 0, stream>>>(edge_src, edge_dst, edge_vals, bcur, bedges);
    wprep_kernel<<<128, 256, 0, stream>>>(weight, wt);
    gemm_mfma_kernel<<<(N_NODES + 63) / 64, 256, 0, stream>>>(x, wt, bias, h);
    gather_fused_kernel<<<NB, 1024, 0, stream>>>(bcur, bedges, h, out);
  } else {
    wprep_kernel<<<128, 256, 0, stream>>>(weight, wt);
    gemm_mfma_kernel<<<(N_NODES + 63) / 64, 256, 0, stream>>>(x, wt, bias, h);
    hipMemsetAsync(d_out, 0, (size_t)out_size * sizeof(float), stream);
    scatter_kernel<<<8192, 256, 0, stream>>>(edge_src, edge_dst, edge_vals, h, out);
  }
}